// Round 6
// baseline (70072.369 us; speedup 1.0000x reference)
//
#include <hip/hip_runtime.h>
#include <hip/hip_bf16.h>

// ContinuousThoughtMachineReLU  (B=32, C=512, N=1024, E=512, D=2048, H=8, hd=64,
//                                T=50, O=1000, NA=512, NO=512)
//
// Round 6: memory-layout round. Rounds 3-5 proved time is invariant to barrier
// implementation; FETCH (80MB/step) fingered redundant activation-panel gloads
// (128x j-slice redundancy) + strided weight/KV reads. Now: KV repacked
// [b][h][n][d]; Wqq [h][na][d]; GEMM weights repacked per-block contiguous
// tiles with 64-block (jsl x ksplit) decomposition; pred fused with entropy;
// dout written via coalesced transpose at end. Flag barrier unchanged.

typedef unsigned short u16;

__device__ __forceinline__ float bf2f(u16 u) {
    return __uint_as_float(((unsigned int)u) << 16);
}
__device__ __forceinline__ float bflo(unsigned int u) { return __uint_as_float(u << 16); }
__device__ __forceinline__ float bfhi(unsigned int u) { return __uint_as_float(u & 0xffff0000u); }
__device__ __forceinline__ u16 f2bf(float f) {
    unsigned int u = __float_as_uint(f);
    unsigned int r = u + 0x7fffu + ((u >> 16) & 1u);
    return (u16)(r >> 16);
}

// L2-bypassing coherent access (relaxed agent atomics; no cache maintenance)
__device__ __forceinline__ float gload(const float* p) {
    return __hip_atomic_load(p, __ATOMIC_RELAXED, __HIP_MEMORY_SCOPE_AGENT);
}
__device__ __forceinline__ void gstore(float* p, float v) {
    __hip_atomic_store(p, v, __ATOMIC_RELAXED, __HIP_MEMORY_SCOPE_AGENT);
}

// ------------------------------------------------- fence-free grid barrier
__device__ __forceinline__ void grid_barrier(unsigned* flags, unsigned* gen, unsigned token)
{
    __syncthreads();
    if (blockIdx.x == 0) {
        if (threadIdx.x == 0)
            __hip_atomic_store(&flags[0], token, __ATOMIC_RELAXED, __HIP_MEMORY_SCOPE_AGENT);
        if (threadIdx.x < 64) {
            unsigned base = threadIdx.x * 4u;
            for (;;) {
                unsigned f0 = __hip_atomic_load(&flags[base + 0], __ATOMIC_RELAXED, __HIP_MEMORY_SCOPE_AGENT);
                unsigned f1 = __hip_atomic_load(&flags[base + 1], __ATOMIC_RELAXED, __HIP_MEMORY_SCOPE_AGENT);
                unsigned f2 = __hip_atomic_load(&flags[base + 2], __ATOMIC_RELAXED, __HIP_MEMORY_SCOPE_AGENT);
                unsigned f3 = __hip_atomic_load(&flags[base + 3], __ATOMIC_RELAXED, __HIP_MEMORY_SCOPE_AGENT);
                if (f0 >= token && f1 >= token && f2 >= token && f3 >= token) break;
                __builtin_amdgcn_s_sleep(1);
            }
        }
        __syncthreads();
        if (threadIdx.x == 0)
            __hip_atomic_store(gen, token, __ATOMIC_RELAXED, __HIP_MEMORY_SCOPE_AGENT);
    } else {
        if (threadIdx.x == 0) {
            __hip_atomic_store(&flags[blockIdx.x], token, __ATOMIC_RELAXED, __HIP_MEMORY_SCOPE_AGENT);
            while (__hip_atomic_load(gen, __ATOMIC_RELAXED, __HIP_MEMORY_SCOPE_AGENT) < token)
                __builtin_amdgcn_s_sleep(2);
        }
        __syncthreads();
    }
}

// ---------------------------------------------------------------- init
__global__ __launch_bounds__(256) void k_init(
    const float* __restrict__ start_state, const float* __restrict__ dec_a,
    const float* __restrict__ dec_o, const int* __restrict__ idx_action,
    float* act_relu, float* selA, float* aA, float* bA, float* aO, float* bO,
    float* r_a, float* r_o, unsigned* barstate)
{
    int g = blockIdx.x * 256 + threadIdx.x;
    int T = gridDim.x * 256;
    for (int i = g; i < 512; i += T) barstate[i] = 0u;
    for (int i = g; i < 32 * 2048; i += T) act_relu[i] = start_state[i & 2047];
    for (int i = g; i < 32 * 512; i += T) selA[i] = start_state[idx_action[i & 511]];
    for (int i = g; i < 256 * 512; i += T) { aA[i] = 0.f; bA[i] = 0.f; }
    for (int i = g; i < 32 * 512; i += T) { aO[i] = 0.f; bO[i] = 0.f; }
    for (int i = g; i < 512; i += T) {
        float da = fminf(fmaxf(dec_a[i], 0.f), 15.f);
        float dv = fminf(fmaxf(dec_o[i], 0.f), 15.f);
        r_a[i] = __expf(-da);
        r_o[i] = __expf(-dv);
    }
}

// ------------------------------------------------- kv = x^T @ W_kv + b_kv (fp32 out)
__global__ __launch_bounds__(256) void k_gemm_xT(
    const float* __restrict__ x, const float* __restrict__ Wkv,
    const float* __restrict__ bkv, float* __restrict__ out)
{
    __shared__ float As[16 * 68];
    __shared__ float Bs[16 * 132];
    int tid = threadIdx.x;
    int tn = tid & 15, tm = tid >> 4;
    int n0 = blockIdx.x * 128;
    int r0 = blockIdx.y * 64;
    int b = r0 >> 10;
    int nrow0 = r0 & 1023;
    const float* xb = x + (size_t)b * 512 * 1024;
    float acc[4][8];
#pragma unroll
    for (int i = 0; i < 4; ++i)
#pragma unroll
        for (int j = 0; j < 8; ++j) acc[i][j] = 0.f;

    for (int k0 = 0; k0 < 512; k0 += 16) {
        __syncthreads();
#pragma unroll
        for (int l = 0; l < 4; ++l) {
            int i = tid + l * 256;
            int nn = i & 63, kk = i >> 6;
            As[kk * 68 + nn] = xb[(size_t)(k0 + kk) * 1024 + nrow0 + nn];
        }
#pragma unroll
        for (int l = 0; l < 8; ++l) {
            int i = tid + l * 256;
            int n = i & 127, kk = i >> 7;
            Bs[kk * 132 + n] = Wkv[(size_t)(k0 + kk) * 512 + n0 + n];
        }
        __syncthreads();
#pragma unroll
        for (int k = 0; k < 16; ++k) {
            float4 a4 = *(const float4*)&As[k * 68 + tm * 4];
            float4 b0 = *(const float4*)&Bs[k * 132 + tn * 8];
            float4 b1 = *(const float4*)&Bs[k * 132 + tn * 8 + 4];
            float av[4] = {a4.x, a4.y, a4.z, a4.w};
            float bv[8] = {b0.x, b0.y, b0.z, b0.w, b1.x, b1.y, b1.z, b1.w};
#pragma unroll
            for (int i = 0; i < 4; ++i)
#pragma unroll
                for (int j = 0; j < 8; ++j) acc[i][j] += av[i] * bv[j];
        }
    }
#pragma unroll
    for (int i = 0; i < 4; ++i) {
        int r = r0 + tm * 4 + i;
        int c = n0 + tn * 8;
        float* orow = out + (size_t)r * 512 + c;
#pragma unroll
        for (int j = 0; j < 8; ++j) orow[j] = acc[i][j] + bkv[c + j];
    }
}

// ------------------------------------------------ fp32 GEMM -> bf16 out, K=512
// mode 0: out[r*N+c]; mode 1 (K/V head-major): out[((r>>10)*8+(c>>6))*65536+(r&1023)*64+(c&63)]
// mode 2 (Wqq h-major): out[(c>>6)*32768 + r*64 + (c&63)]
__global__ __launch_bounds__(256) void k_gemm_AB(
    const float* __restrict__ A, int lda,
    const float* __restrict__ B, int ldb,
    const float* __restrict__ bias,
    u16* __restrict__ out, int N, int mode)
{
    __shared__ float As[16 * 68];
    __shared__ float Bs[16 * 132];
    int tid = threadIdx.x;
    int tn = tid & 15, tm = tid >> 4;
    int n0 = blockIdx.x * 128;
    int r0 = blockIdx.y * 64;
    float acc[4][8];
#pragma unroll
    for (int i = 0; i < 4; ++i)
#pragma unroll
        for (int j = 0; j < 8; ++j) acc[i][j] = 0.f;

    for (int k0 = 0; k0 < 512; k0 += 16) {
        __syncthreads();
#pragma unroll
        for (int l = 0; l < 4; ++l) {
            int i = tid + l * 256;
            int kk = i & 15, m = i >> 4;
            As[kk * 68 + m] = A[(size_t)(r0 + m) * lda + k0 + kk];
        }
#pragma unroll
        for (int l = 0; l < 8; ++l) {
            int i = tid + l * 256;
            int n = i & 127, kk = i >> 7;
            Bs[kk * 132 + n] = B[(size_t)(k0 + kk) * ldb + n0 + n];
        }
        __syncthreads();
#pragma unroll
        for (int k = 0; k < 16; ++k) {
            float4 a4 = *(const float4*)&As[k * 68 + tm * 4];
            float4 b0 = *(const float4*)&Bs[k * 132 + tn * 8];
            float4 b1 = *(const float4*)&Bs[k * 132 + tn * 8 + 4];
            float av[4] = {a4.x, a4.y, a4.z, a4.w};
            float bv[8] = {b0.x, b0.y, b0.z, b0.w, b1.x, b1.y, b1.z, b1.w};
#pragma unroll
            for (int i = 0; i < 4; ++i)
#pragma unroll
                for (int j = 0; j < 8; ++j) acc[i][j] += av[i] * bv[j];
        }
    }
#pragma unroll
    for (int i = 0; i < 4; ++i) {
        int r = r0 + tm * 4 + i;
        int c = n0 + tn * 8;
        float vv[8];
#pragma unroll
        for (int j = 0; j < 8; ++j) vv[j] = acc[i][j] + (bias ? bias[c + j] : 0.f);
        unsigned int w0 = (unsigned int)f2bf(vv[0]) | ((unsigned int)f2bf(vv[1]) << 16);
        unsigned int w1 = (unsigned int)f2bf(vv[2]) | ((unsigned int)f2bf(vv[3]) << 16);
        unsigned int w2 = (unsigned int)f2bf(vv[4]) | ((unsigned int)f2bf(vv[5]) << 16);
        unsigned int w3 = (unsigned int)f2bf(vv[6]) | ((unsigned int)f2bf(vv[7]) << 16);
        size_t oidx;
        if (mode == 0)      oidx = (size_t)r * N + c;
        else if (mode == 1) oidx = (size_t)((r >> 10) * 8 + (c >> 6)) * 65536 + (size_t)(r & 1023) * 64 + (c & 63);
        else                oidx = (size_t)(c >> 6) * 32768 + (size_t)r * 64 + (c & 63);
        *(uint4*)&out[oidx] = make_uint4(w0, w1, w2, w3);
    }
}

// ------------------------------------------------- in-place LN over kv rows (512 wide)
__global__ __launch_bounds__(256) void k_ln_kv(
    float* __restrict__ kv, const float* __restrict__ g, const float* __restrict__ be)
{
    int tid = threadIdx.x;
    int lane = tid & 63;
    int row = blockIdx.x * 4 + (tid >> 6);
    float* p = kv + (size_t)row * 512 + lane * 8;
    float4 u0 = *(float4*)p;
    float4 u1 = *(float4*)(p + 4);
    float v[8] = {u0.x, u0.y, u0.z, u0.w, u1.x, u1.y, u1.z, u1.w};
    float s = 0.f, s2 = 0.f;
#pragma unroll
    for (int i = 0; i < 8; ++i) { s += v[i]; s2 += v[i] * v[i]; }
#pragma unroll
    for (int off = 32; off >= 1; off >>= 1) {
        s += __shfl_xor(s, off, 64);
        s2 += __shfl_xor(s2, off, 64);
    }
    float m = s * (1.f / 512.f);
    float var = s2 * (1.f / 512.f) - m * m;
    float rs = rsqrtf(var + 1e-5f);
    const float* gp = g + lane * 8;
    const float* bp = be + lane * 8;
#pragma unroll
    for (int i = 0; i < 8; ++i) v[i] = (v[i] - m) * rs * gp[i] + bp[i];
    *(float4*)p = make_float4(v[0], v[1], v[2], v[3]);
    *(float4*)(p + 4) = make_float4(v[4], v[5], v[6], v[7]);
}

// ---------------------------------------------- bias-fold: out[j] = vin@B[:,j] + badd[j]
__global__ __launch_bounds__(256) void k_bvec(
    const float* __restrict__ vin, const float* __restrict__ B, int ldb,
    const float* __restrict__ badd, float* __restrict__ out, int Nj)
{
    int j = blockIdx.x * 256 + threadIdx.x;
    if (j >= Nj) return;
    float s = 0.f;
    for (int e = 0; e < 512; ++e) s += vin[e] * B[(size_t)e * ldb + j];
    out[j] = s + badd[j];
}

// ---------------------------------------------- f32 -> bf16 convert
__global__ __launch_bounds__(256) void k_convert(
    const float* __restrict__ src, u16* __restrict__ dst, int n)
{
    int g = blockIdx.x * 256 + threadIdx.x;
    int T = gridDim.x * 256;
    for (int i = g; i < n; i += T) dst[i] = f2bf(src[i]);
}

// ---------------------------------------------- weight retile: [K][N] -> per-block tiles
// tile = (k/KR)*(N>>7) + (j>>7); dst[tile][k%KR][j&127]
__global__ __launch_bounds__(256) void k_retile(
    const u16* __restrict__ src, u16* __restrict__ dst, int K, int shiftN, int KR)
{
    int g = blockIdx.x * 256 + threadIdx.x;
    int T = gridDim.x * 256;
    int N = 1 << shiftN;
    int n_jsl = N >> 7;
    int total = K << shiftN;
    for (int i = g; i < total; i += T) {
        int k = i >> shiftN;
        int j = i & (N - 1);
        int ks = k / KR;
        int kl = k - ks * KR;
        size_t di = ((size_t)(ks * n_jsl + (j >> 7)) * KR + kl) * 128 + (j & 127);
        dst[di] = src[i];
    }
}

// ================================================================ loop phase bodies

// fused syncA + attention for (b,h); smem >= 1856 floats
__device__ void d_attn(const float* __restrict__ selA, const float* __restrict__ r_a,
                       float* __restrict__ aAp, float* __restrict__ bAp,
                       const u16* __restrict__ Wqq, const float* __restrict__ bqq,
                       const u16* __restrict__ Kh, const u16* __restrict__ Vh,
                       float* __restrict__ attn, int b, int h, float* smem)
{
    float* sA  = smem;          // 512
    float* qh  = smem + 512;    // 64
    float* sc  = smem + 576;    // 1024
    float* red = smem + 1600;   // 256
    int tid = threadIdx.x;

#pragma unroll
    for (int q = 0; q < 2; ++q) {
        int j = q * 256 + tid;
        float sel = gload(&selA[b * 512 + j]);
        float r = r_a[j];
        float a = r * aAp[j] + sel * sel;
        float bb = r * bAp[j] + 1.f;
        aAp[j] = a; bAp[j] = bb;
        sA[j] = a * rsqrtf(bb);
    }
    __syncthreads();

    {   // qh: Wqq [h][na][d] contiguous stream
        int d = tid & 63, kg = tid >> 6;
        const u16* wp = Wqq + (size_t)h * 32768 + (size_t)(kg * 128) * 64 + d;
        const float* ap = sA + kg * 128;
        float p = 0.f;
#pragma unroll 8
        for (int na = 0; na < 128; ++na) p += ap[na] * bf2f(wp[na * 64]);
        red[tid] = p;
    }
    __syncthreads();
    if (tid < 64) qh[tid] = red[tid] + red[tid + 64] + red[tid + 128] + red[tid + 192] + bqq[h * 64 + tid];
    __syncthreads();

    // scores: K [n][64] rows contiguous (128B each)
#pragma unroll
    for (int rr = 0; rr < 4; ++rr) {
        int n = rr * 256 + tid;
        const uint4* kp = (const uint4*)(Kh + (size_t)n * 64);
        float dot = 0.f;
#pragma unroll
        for (int i = 0; i < 8; ++i) {
            uint4 u = kp[i];
            float4 q0 = *(float4*)&qh[i * 8];
            float4 q1 = *(float4*)&qh[i * 8 + 4];
            dot += q0.x * bflo(u.x) + q0.y * bfhi(u.x)
                 + q0.z * bflo(u.y) + q0.w * bfhi(u.y)
                 + q1.x * bflo(u.z) + q1.y * bfhi(u.z)
                 + q1.z * bflo(u.w) + q1.w * bfhi(u.w);
        }
        sc[n] = dot * 0.125f;
    }
    __syncthreads();

    float mx = fmaxf(fmaxf(sc[tid], sc[tid + 256]), fmaxf(sc[tid + 512], sc[tid + 768]));
    red[tid] = mx;
    __syncthreads();
    for (int s = 128; s > 0; s >>= 1) {
        if (tid < s) red[tid] = fmaxf(red[tid], red[tid + s]);
        __syncthreads();
    }
    float bmax = red[0];
    __syncthreads();
    float zs = 0.f;
#pragma unroll
    for (int rr = 0; rr < 4; ++rr) {
        int n = rr * 256 + tid;
        float e = __expf(sc[n] - bmax);
        sc[n] = e;
        zs += e;
    }
    red[tid] = zs;
    __syncthreads();
    for (int s = 128; s > 0; s >>= 1) {
        if (tid < s) red[tid] += red[tid + s];
        __syncthreads();
    }
    float Zinv = 1.f / red[0];
    __syncthreads();

    {   // V pass: per n, wave reads V[n][0..63] = 128B contiguous
        int d = tid & 63, ng = tid >> 6;
        const u16* Vp = Vh + d;
        float acc = 0.f;
        int nb = ng * 256;
#pragma unroll 8
        for (int n = nb; n < nb + 256; ++n) acc += sc[n] * bf2f(Vp[(size_t)n * 64]);
        red[tid] = acc;
    }
    __syncthreads();
    if (tid < 64) {
        float a = (red[tid] + red[tid + 64] + red[tid + 128] + red[tid + 192]) * Zinv;
        gstore(&attn[b * 512 + h * 64 + tid], a);
    }
    __syncthreads();
}

// tiled skinny GEMM partial: block covers 128 j x KR k; weight tile contiguous.
// A = [A1 (K1 cols) | A2], optional relu(x+tb1) on A1. 16 atomicAdds/thread.
__device__ void d_skinny2(const float* __restrict__ A1, int K1, const float* __restrict__ tb1,
                          const float* __restrict__ A2, int K2,
                          const u16* __restrict__ Wt, int KR, int kbeg,
                          int j0, float* __restrict__ out, int N, float* smem)
{
    float* Al = smem;   // [64][36]
    int tid = threadIdx.x;
    int jl = tid & 31, rg = tid >> 5;
    float acc[4][4];
#pragma unroll
    for (int s = 0; s < 4; ++s)
#pragma unroll
        for (int r = 0; r < 4; ++r) acc[s][r] = 0.f;

    for (int kc = 0; kc < KR; kc += 64) {
        __syncthreads();
#pragma unroll
        for (int l = 0; l < 8; ++l) {
            int i = tid + l * 256;
            int r = i >> 6, k = i & 63;
            int kk = kbeg + kc + k;
            float v;
            if (kk < K1) {
                v = gload(&A1[r * K1 + kk]);
                if (tb1) v = fmaxf(0.f, v + tb1[kk]);
            } else {
                v = gload(&A2[r * K2 + kk - K1]);
            }
            Al[k * 36 + r] = v;
        }
        __syncthreads();
        const u16* wrow = Wt + (size_t)kc * 128;
#pragma unroll 8
        for (int k = 0; k < 64; ++k) {
            uint2 wv = *(const uint2*)(wrow + (size_t)k * 128 + jl * 4);
            float w0 = bflo(wv.x), w1 = bfhi(wv.x), w2 = bflo(wv.y), w3 = bfhi(wv.y);
            float4 a = *(const float4*)&Al[k * 36 + rg * 4];
            float av[4] = {a.x, a.y, a.z, a.w};
#pragma unroll
            for (int r = 0; r < 4; ++r) {
                acc[0][r] += av[r] * w0;
                acc[1][r] += av[r] * w1;
                acc[2][r] += av[r] * w2;
                acc[3][r] += av[r] * w3;
            }
        }
    }
    int jb = j0 + jl * 4;
#pragma unroll
    for (int s = 0; s < 4; ++s)
#pragma unroll
        for (int r = 0; r < 4; ++r)
            atomicAdd(&out[(size_t)(rg * 4 + r) * N + jb + s], acc[s][r]);
    __syncthreads();
}

__device__ __forceinline__ void blk_reduce2(float& s, float& s2, float* red, int tid)
{
#pragma unroll
    for (int off = 32; off >= 1; off >>= 1) {
        s += __shfl_xor(s, off, 64);
        s2 += __shfl_xor(s2, off, 64);
    }
    __syncthreads();
    if ((tid & 63) == 0) { red[(tid >> 6) * 2] = s; red[(tid >> 6) * 2 + 1] = s2; }
    __syncthreads();
    s = red[0] + red[2] + red[4] + red[6];
    s2 = red[1] + red[3] + red[5] + red[7];
    __syncthreads();
}

__device__ void d_glu(const float* __restrict__ h_pre, const float* __restrict__ bcomb,
                      const float* __restrict__ gsyn, const float* __restrict__ besyn,
                      const float* __restrict__ gpm, const float* __restrict__ bepm,
                      float* __restrict__ hpm, int b, float* smem)
{
    float* red = smem;
    int tid = threadIdx.x;
    const float* hr = h_pre + (size_t)b * 4096;
    float zv[8];
    float s = 0.f, s2 = 0.f;
#pragma unroll
    for (int q = 0; q < 8; ++q) {
        int i = q * 256 + tid;
        float av = gload(&hr[i]) + bcomb[i];
        float gv = gload(&hr[2048 + i]) + bcomb[2048 + i];
        float z = av / (1.f + __expf(-gv));
        zv[q] = z; s += z; s2 += z * z;
    }
    blk_reduce2(s, s2, red, tid);
    float m1 = s * (1.f / 2048.f);
    float v1 = s2 * (1.f / 2048.f) - m1 * m1;
    float rs1 = rsqrtf(v1 + 1e-5f);
    float t = 0.f, t2 = 0.f;
#pragma unroll
    for (int q = 0; q < 8; ++q) {
        int i = q * 256 + tid;
        float st = (zv[q] - m1) * rs1 * gsyn[i] + besyn[i];
        zv[q] = st; t += st; t2 += st * st;
    }
    blk_reduce2(t, t2, red, tid);
    float m2 = t * (1.f / 2048.f);
    float v2 = t2 * (1.f / 2048.f) - m2 * m2;
    float rs2 = rsqrtf(v2 + 1e-5f);
#pragma unroll
    for (int q = 0; q < 8; ++q) {
        int i = q * 256 + tid;
        gstore(&hpm[(size_t)b * 2048 + i], (zv[q] - m2) * rs2 * gpm[i] + bepm[i]);
    }
}

// ================================================================ persistent loop
struct LoopP {
    const float *b1, *b2;
    const int *idx_action, *idx_out;
    const float *r_a, *r_o;
    float *aA, *bA, *aO, *bO;
    float *act_relu, *selA, *h_pre, *hpm, *t1, *actnext, *attn, *pred_t;
    const u16 *Wqq, *Kb, *Vb, *Wt3, *Wt1, *Wt2, *Woutb;
    const float *bqq, *bcomb, *gsyn, *besyn, *gpm, *bepm, *b_out;
    float *out;
    unsigned *flags, *gen;
};

__global__ __launch_bounds__(256, 2) void k_loop(LoopP P)
{
    __shared__ float smem[4096];
    int blk = blockIdx.x, tid = threadIdx.x;
    int b8 = blk >> 3, h = blk & 7;
    unsigned tok = 0;

    float* aAp = P.aA + blk * 512;
    float* bAp = P.bA + blk * 512;
    const float lg1000 = logf(1000.0f);

    for (int t = 0; t < 50; ++t) {
        // ---- P12: zero scratch slices + fused syncA+attention (all 256 blocks)
        {
            int i1 = blk * 512 + tid;
            gstore(&P.h_pre[i1], 0.f);
            gstore(&P.h_pre[i1 + 256], 0.f);
            int i2 = blk * 256 + tid;
            gstore(&P.t1[i2], 0.f);
            gstore(&P.actnext[i2], 0.f);
        }
        d_attn(P.selA, P.r_a, aAp, bAp, P.Wqq, P.bqq,
               P.Kb + (size_t)blk * 65536, P.Vb + (size_t)blk * 65536,
               P.attn, b8, h, smem);
        grid_barrier(P.flags, P.gen, ++tok);

        // ---- P3: h_pre = [attn | act_relu] @ W_comb  (32 jsl x 2 ks = 64 blocks)
        if (blk < 64) {
            int jsl = blk & 31, ks = blk >> 5;
            d_skinny2(P.attn, 512, nullptr, P.act_relu, 2048,
                      P.Wt3 + (size_t)(ks * 32 + jsl) * (1280 * 128),
                      1280, ks * 1280, jsl * 128, P.h_pre, 4096, smem);
        }
        grid_barrier(P.flags, P.gen, ++tok);

        // ---- P4: GLU + double LN (32 blocks)
        if (blk < 32) d_glu(P.h_pre, P.bcomb, P.gsyn, P.besyn, P.gpm, P.bepm, P.hpm, blk, smem);
        grid_barrier(P.flags, P.gen, ++tok);

        // ---- P5: t1 = hpm @ W1  (16 jsl x 4 ks = 64 blocks)
        if (blk < 64) {
            int jsl = blk & 15, ks = blk >> 4;
            d_skinny2(P.hpm, 2048, nullptr, nullptr, 0,
                      P.Wt1 + (size_t)(ks * 16 + jsl) * (512 * 128),
                      512, ks * 512, jsl * 128, P.t1, 2048, smem);
        }
        grid_barrier(P.flags, P.gen, ++tok);

        // ---- P6: actnext = relu(t1+b1) @ W2
        if (blk < 64) {
            int jsl = blk & 15, ks = blk >> 4;
            d_skinny2(P.t1, 2048, P.b1, nullptr, 0,
                      P.Wt2 + (size_t)(ks * 16 + jsl) * (512 * 128),
                      512, ks * 512, jsl * 128, P.actnext, 2048, smem);
        }
        grid_barrier(P.flags, P.gen, ++tok);

        // ---- P78: act_relu/selA production + syncO + pred + entropy (32 blocks)
        if (blk < 32) {
            int b = blk;
            float* arl = smem;          // 2048
            float* sO  = smem + 2048;   // 512
            float* p   = smem + 2560;   // 1000
            float* red = smem + 3560;   // 8
#pragma unroll
            for (int q = 0; q < 8; ++q) {
                int k = q * 256 + tid;
                float v = fmaxf(0.f, gload(&P.actnext[b * 2048 + k]) + P.b2[k]);
                arl[k] = v;
                gstore(&P.act_relu[b * 2048 + k], v);
            }
            __syncthreads();
            float* aOp = P.aO + b * 512;
            float* bOp = P.bO + b * 512;
#pragma unroll
            for (int q = 0; q < 2; ++q) {
                int j = q * 256 + tid;
                gstore(&P.selA[b * 512 + j], arl[P.idx_action[j]]);
                float v = arl[P.idx_out[j]];
                float r = P.r_o[j];
                float a = r * aOp[j] + v * v;
                float bb = r * bOp[j] + 1.f;
                aOp[j] = a; bOp[j] = bb;
                float sy = a * rsqrtf(bb);
                sO[j] = sy;
                if (t == 49) P.out[1603200 + b * 512 + j] = sy;
            }
            __syncthreads();
            // pred row (1000 outputs) from LDS sO x Wout (k-major)
#pragma unroll
            for (int q = 0; q < 4; ++q) {
                int j = q * 256 + tid;
                if (j < 1000) {
                    float s = 0.f;
#pragma unroll 8
                    for (int k = 0; k < 512; ++k) s += sO[k] * bf2f(P.Woutb[(size_t)k * 1000 + j]);
                    float pv = s + P.b_out[j];
                    p[j] = pv;
                    gstore(&P.pred_t[(size_t)t * 32000 + b * 1000 + j], pv);
                }
            }
            __syncthreads();
            // entropy of softmax(pred)
            float mx = -1e30f;
            for (int i = tid; i < 1000; i += 256) mx = fmaxf(mx, p[i]);
#pragma unroll
            for (int off = 32; off >= 1; off >>= 1) mx = fmaxf(mx, __shfl_xor(mx, off, 64));
            __syncthreads();
            if ((tid & 63) == 0) red[tid >> 6] = mx;
            __syncthreads();
            mx = fmaxf(fmaxf(red[0], red[1]), fmaxf(red[2], red[3]));
            float zs = 0.f;
            for (int i = tid; i < 1000; i += 256) zs += __expf(p[i] - mx);
#pragma unroll
            for (int off = 32; off >= 1; off >>= 1) zs += __shfl_xor(zs, off, 64);
            __syncthreads();
            if ((tid & 63) == 0) red[tid >> 6] = zs;
            __syncthreads();
            float Z = red[0] + red[1] + red[2] + red[3];
            float logZ = __logf(Z);
            float se = 0.f;
            for (int i = tid; i < 1000; i += 256) {
                float lp = p[i] - mx - logZ;
                se += __expf(lp) * lp;
            }
#pragma unroll
            for (int off = 32; off >= 1; off >>= 1) se += __shfl_xor(se, off, 64);
            __syncthreads();
            if ((tid & 63) == 0) red[tid >> 6] = se;
            __syncthreads();
            if (tid == 0) {
                float ne = -(red[0] + red[1] + red[2] + red[3]) / lg1000;
                P.out[1600000 + b * 100 + t] = ne;
                P.out[1600000 + b * 100 + 50 + t] = 1.f - ne;
            }
        }
        grid_barrier(P.flags, P.gen, ++tok);
    }

    // ---- final: transpose pred_t[t][b][j] -> out[b][j][t] (coalesced both sides)
    if (blk < 32) {
        int b = blk;
#pragma unroll 1
        for (int c = 0; c < 4; ++c) {
            int i = c * 256 + tid;
            if (i < 1000) {
                float v[50];
#pragma unroll
                for (int t = 0; t < 50; ++t)
                    v[t] = gload(&P.pred_t[(size_t)t * 32000 + b * 1000 + i]);
                float* dp = P.out + (size_t)b * 50000 + (size_t)i * 50;
#pragma unroll
                for (int t = 0; t < 50; ++t) dp[t] = v[t];
            }
        }
    }
}

// ================================================================ host launcher
extern "C" void kernel_launch(void* const* d_in, const int* in_sizes, int n_in,
                              void* d_out, int out_size, void* d_ws, size_t ws_size,
                              hipStream_t stream)
{
    const float* x      = (const float*)d_in[0];
    const float* W_kv   = (const float*)d_in[1];
    const float* b_kv   = (const float*)d_in[2];
    const float* g_kv   = (const float*)d_in[3];
    const float* be_kv  = (const float*)d_in[4];
    const float* W_q    = (const float*)d_in[5];
    const float* b_q    = (const float*)d_in[6];
    const float* W_in   = (const float*)d_in[7];
    const float* b_in   = (const float*)d_in[8];
    const float* W_ao   = (const float*)d_in[9];
    const float* b_ao   = (const float*)d_in[10];
    const float* W_syn  = (const float*)d_in[11];
    const float* b_syn  = (const float*)d_in[12];
    const float* g_syn  = (const float*)d_in[13];
    const float* be_syn = (const float*)d_in[14];
    const float* g_pm   = (const float*)d_in[15];
    const float* be_pm  = (const float*)d_in[16];
    const float* W1     = (const float*)d_in[17];
    const float* b1     = (const float*)d_in[18];
    const float* W2     = (const float*)d_in[19];
    const float* b2     = (const float*)d_in[20];
    const float* start_state  = (const float*)d_in[21];
    const float* decay_action = (const float*)d_in[22];
    const float* decay_out    = (const float*)d_in[23];
    const float* W_out  = (const float*)d_in[24];
    const float* b_out  = (const float*)d_in[25];
    const int* idx_action = (const int*)d_in[26];
    const int* idx_out    = (const int*)d_in[27];
    float* out = (float*)d_out;

    char* ws = (char*)d_ws;
    size_t off = 0;
    auto take = [&](size_t bytes) -> char* {
        char* p = ws + off;
        off += (bytes + 255) & ~(size_t)255;
        return p;
    };

    // region0 (80MB): kv fp32 [0,64M) precompute-only; then weights + tiles
    char* region0 = take(83886080);
    float* kv = (float*)region0;
    u16* W_full = (u16*)region0;                       // 2560x4096 bf16 = 20.97M
    u16* W1b    = (u16*)(region0 + 20971520);          // 8.39M
    u16* W2b    = (u16*)(region0 + 29360128);          // 8.39M
    u16* Woutb  = (u16*)(region0 + 37748736);          // 1.02M
    u16* Wqqb   = (u16*)(region0 + 38772736);          // 0.52M (h-major)
    u16* Wt3    = (u16*)(region0 + 39297024);          // 20.97M tiles
    u16* Wt1    = (u16*)(region0 + 60268544);          // 8.39M
    u16* Wt2    = (u16*)(region0 + 68657152);          // 8.39M -> 77.05M < 80M

    u16* K_bf = (u16*)take(33554432);   // [b][h][n][d]
    u16* V_bf = (u16*)take(33554432);
    float* b_qq   = (float*)take(2048);
    float* b_comb = (float*)take(16384);
    float* r_a = (float*)take(2048);
    float* r_o = (float*)take(2048);
    float* aA = (float*)take(524288);   // 256 x 512 (per (b,h) private)
    float* bA = (float*)take(524288);
    float* aO = (float*)take(65536);
    float* bO = (float*)take(65536);
    float* selA = (float*)take(65536);
    float* act_relu = (float*)take(262144);
    float* h_pre = (float*)take(524288);
    float* hpm   = (float*)take(262144);
    float* t1_pre = (float*)take(262144);
    float* attnb = (float*)take(65536);
    float* pred_t = (float*)take(6400000);  // [50][32][1000]
    unsigned* barstate = (unsigned*)take(2048);
    unsigned* flagsp = barstate;
    unsigned* genp   = barstate + 384;
    (void)ws_size; (void)in_sizes; (void)n_in; (void)out_size;

    // ---------------- precompute ----------------
    k_init<<<256, 256, 0, stream>>>(start_state, decay_action, decay_out, idx_action,
                                    act_relu, selA, aA, bA, aO, bO, r_a, r_o, barstate);
    k_gemm_xT<<<dim3(4, 512), 256, 0, stream>>>(x, W_kv, b_kv, kv);
    k_ln_kv<<<8192, 256, 0, stream>>>(kv, g_kv, be_kv);
    k_gemm_AB<<<dim3(4, 512), 256, 0, stream>>>(kv, 512, W_in + 512, 1536, b_in + 512, K_bf, 512, 1);
    k_gemm_AB<<<dim3(4, 512), 256, 0, stream>>>(kv, 512, W_in + 1024, 1536, b_in + 1024, V_bf, 512, 1);
    k_gemm_AB<<<dim3(4, 8), 256, 0, stream>>>(W_q, 512, W_in, 1536, nullptr, Wqqb, 512, 2);
    k_gemm_AB<<<dim3(32, 8), 256, 0, stream>>>(W_ao, 512, W_syn, 4096, nullptr, W_full, 4096, 0);
    k_bvec<<<2, 256, 0, stream>>>(b_q, W_in, 1536, b_in, b_qq, 512);
    k_bvec<<<16, 256, 0, stream>>>(b_ao, W_syn, 4096, b_syn, b_comb, 4096);
    k_convert<<<2048, 256, 0, stream>>>(W_syn + (size_t)512 * 4096, W_full + (size_t)512 * 4096, 2048 * 4096);
    k_convert<<<2048, 256, 0, stream>>>(W1, W1b, 2048 * 2048);
    k_convert<<<2048, 256, 0, stream>>>(W2, W2b, 2048 * 2048);
    k_convert<<<512, 256, 0, stream>>>(W_out, Woutb, 512 * 1000);
    k_retile<<<2048, 256, 0, stream>>>(W_full, Wt3, 2560, 12, 1280);
    k_retile<<<2048, 256, 0, stream>>>(W1b, Wt1, 2048, 11, 512);
    k_retile<<<2048, 256, 0, stream>>>(W2b, Wt2, 2048, 11, 512);

    // ---------------- recurrent loop: ONE persistent kernel ----------------
    LoopP P;
    P.b1 = b1; P.b2 = b2;
    P.idx_action = idx_action; P.idx_out = idx_out;
    P.r_a = r_a; P.r_o = r_o;
    P.aA = aA; P.bA = bA; P.aO = aO; P.bO = bO;
    P.act_relu = act_relu; P.selA = selA;
    P.h_pre = h_pre; P.hpm = hpm; P.t1 = t1_pre; P.actnext = t1_pre; // placeholder fix below
    P.actnext = (float*)take(262144);
    P.attn = attnb; P.pred_t = pred_t;
    P.Wqq = Wqqb; P.Kb = K_bf; P.Vb = V_bf;
    P.Wt3 = Wt3; P.Wt1 = Wt1; P.Wt2 = Wt2; P.Woutb = Woutb;
    P.bqq = b_qq; P.bcomb = b_comb;
    P.gsyn = g_syn; P.besyn = be_syn; P.gpm = g_pm; P.bepm = be_pm;
    P.b_out = b_out;
    P.out = out;
    P.flags = flagsp; P.gen = genp;

    k_loop<<<256, 256, 0, stream>>>(P);
}